// Round 17
// baseline (1290.888 us; speedup 1.0000x reference)
//
#include <hip/hip_runtime.h>
#include <math.h>

// GraphNet: 2x EdgeConv (E=800k, F=H=64) + BN folded/commuted + pooling.
// R17: pass2p's VALU GEMM-b (282us @70% VALU, ~140 instr/edge) replaced by
// MFMA-pull k_pass2m: per node, 16 CSR-contiguous edges/group; B-frags built
// in-register (layout = R6-proven spill layout), A = W' in LDS (R9-proven
// swizzle+frag reads), 16 mfma_16x16x32_bf16/group, D->(edge,ch) mapping
// proven. Stats+max in regs, xor-reduce + plain store per node.
// Also: 4-edge ILP in pass1p/pass3p (R14 lesson).

typedef unsigned short u16;
typedef unsigned int   u32;
typedef __bf16 bf16x8 __attribute__((ext_vector_type(8)));
typedef float  f32x4  __attribute__((ext_vector_type(4)));
typedef unsigned short us4 __attribute__((ext_vector_type(4)));
typedef _Float16 f16;
typedef f16 f16x2 __attribute__((ext_vector_type(2)));

#define EPSBN 1e-5f
#define PB_TOT 9344
// pblk: 0:stS1a[128] 128:stQ1a[128] 256:stS1b 320:stQ1b 384:stS2 448:stQ2
// 512:s1a[128] 640:t1a[128] 768:b1bF[64] 832:s1b 896:t1b 960:s2 1024:t2
// 1088:gmax[4096] 5184:gsum[4096] 9280:cnt[64]

__device__ __forceinline__ u32 f2bf1(float f){
    u32 u = __float_as_uint(f);
    return (u + 0x7FFFu + ((u >> 16) & 1u)) >> 16;
}
__device__ __forceinline__ float bf2f(u16 b){
    return __uint_as_float(((u32)b) << 16);
}
__device__ __forceinline__ void atomicMaxF(float* a, float v){
    if (v >= 0.f) atomicMax((int*)a, __float_as_int(v));
    else          atomicMin((u32*)a, __float_as_uint(v));
}
__device__ __forceinline__ int swz(int row, int k){
    return row*128 + (k ^ ((row & 7) << 3));
}
__device__ __forceinline__ int swz64(int row, int k){
    return row*64 + (k ^ ((row & 7) << 3));
}
__device__ __forceinline__ f32x4 mfma16(bf16x8 a, bf16x8 b, f32x4 c){
    return __builtin_amdgcn_mfma_f32_16x16x32_bf16(a, b, c, 0, 0, 0);
}
// packed f16 pair + relu -> packed bf16 word
__device__ __forceinline__ u32 hpack(u32 praw, u32 qraw){
    f16x2 p = __builtin_bit_cast(f16x2, praw);
    f16x2 q = __builtin_bit_cast(f16x2, qraw);
    f16x2 h = p + q;
    float h0 = fmaxf((float)h[0], 0.f);
    float h1 = fmaxf((float)h[1], 0.f);
    return f2bf1(h0) | (f2bf1(h1) << 16);
}

__global__ void k_init(const float* __restrict__ x, u16* __restrict__ xb,
                       float* __restrict__ agg,
                       float* __restrict__ pblk, int* __restrict__ deg,
                       int NF, int N){
    int i = blockIdx.x*256 + threadIdx.x;
    if (i < NF){
        xb[i] = (u16)f2bf1(x[i]);
        agg[i] = -INFINITY;
    }
    if (i < N) deg[i] = 0;
    if (i < PB_TOT){
        pblk[i] = (i >= 1088 && i < 5184) ? -INFINITY : 0.f;
    }
}

__global__ void k_hist(const int* __restrict__ edst, int* __restrict__ deg, int E){
    int e = blockIdx.x*256 + threadIdx.x;
    if (e < E) atomicAdd(&deg[edst[e]], 1);
}

// 3-kernel parallel exclusive scan of deg -> cursor.
__global__ __launch_bounds__(1024) void k_scanA(const int* __restrict__ deg,
                                                int* __restrict__ cursor,
                                                int* __restrict__ bsum, int N){
    __shared__ int buf[1024];
    int tid = threadIdx.x;
    int i = blockIdx.x*1024 + tid;
    int v = (i < N) ? deg[i] : 0;
    buf[tid] = v;
    __syncthreads();
    #pragma unroll
    for (int s = 1; s < 1024; s <<= 1){
        int a = (tid >= s) ? buf[tid - s] : 0;
        __syncthreads();
        buf[tid] += a;
        __syncthreads();
    }
    if (i < N) cursor[i] = buf[tid] - v;
    if (tid == 1023) bsum[blockIdx.x] = buf[1023];
}
__global__ void k_scanB(const int* __restrict__ bsum, int* __restrict__ boff, int nblk){
    if (threadIdx.x == 0){
        int run = 0;
        for (int i = 0; i < nblk; ++i){ boff[i] = run; run += bsum[i]; }
    }
}
__global__ __launch_bounds__(1024) void k_scanC(int* __restrict__ cursor,
                                                const int* __restrict__ boff, int N){
    int i = blockIdx.x*1024 + threadIdx.x;
    if (i < N) cursor[i] += boff[blockIdx.x];
}

__global__ void k_scatter(const int* __restrict__ esrc, const int* __restrict__ edst,
                          int* __restrict__ cursor, int* __restrict__ eps, int E){
    int e = blockIdx.x*256 + threadIdx.x;
    if (e < E){
        int d = edst[e];
        int pos = atomicAdd(&cursor[d], 1);
        eps[pos] = esrc[e];
    }
}

// Node GEMM -> PQ table. FMT=0: bf16 out; FMT=1: f16 out.
template<int COUT, int FMT>
__global__ __launch_bounds__(256) void k_ngemm(
    const u16* __restrict__ xin, const float* __restrict__ Wsrc,
    const float* __restrict__ bias, u16* __restrict__ PQ, int N)
{
    const int WC = COUT/2;
    __shared__ u16 Wt[COUT*64];
    __shared__ u16 At[64*64];
    int tid = threadIdx.x;
    for (int i = tid; i < COUT*64; i += 256){
        int c = i >> 6, k = i & 63;
        float w = (c < WC) ? (Wsrc[k*WC + c] - Wsrc[(64+k)*WC + c])
                           : Wsrc[(64+k)*WC + (c - WC)];
        Wt[swz64(c, k)] = (u16)f2bf1(w);
    }
    int t = blockIdx.x;
    for (int i = tid; i < 512; i += 256){
        int row = i >> 3, ck = i & 7;
        int node = t*64 + row;
        uint4 v;
        if (node < N) v = *(const uint4*)(xin + (size_t)node*64 + ck*8);
        else { v.x = v.y = v.z = v.w = 0u; }
        *(uint4*)&At[swz64(row, ck*8)] = v;
    }
    __syncthreads();
    int lane = tid & 63, wave = tid >> 6;
    int lg = lane >> 4, lr = lane & 15;
    int row = wave*16 + lr;
    bf16x8 bfr[2];
    #pragma unroll
    for (int kt = 0; kt < 2; kt++)
        bfr[kt] = *(const bf16x8*)&At[swz64(row, kt*32 + lg*8)];
    int node = t*64 + wave*16 + lr;
    #pragma unroll
    for (int mt = 0; mt < COUT/16; mt++){
        f32x4 acc = {0.f,0.f,0.f,0.f};
        #pragma unroll
        for (int kt = 0; kt < 2; kt++){
            bf16x8 af = *(const bf16x8*)&Wt[swz64(mt*16 + lr, kt*32 + lg*8)];
            acc = mfma16(af, bfr[kt], acc);
        }
        int ch = mt*16 + lg*4;
        float r[4] = {acc[0], acc[1], acc[2], acc[3]};
        if (ch < WC){
            float4 bb = *(const float4*)(bias + ch);
            r[0] += bb.x; r[1] += bb.y; r[2] += bb.z; r[3] += bb.w;
        }
        if (node < N){
            us4 w4;
            #pragma unroll
            for (int j = 0; j < 4; j++){
                if (FMT){
                    f16 hf = (f16)r[j];
                    w4[j] = __builtin_bit_cast(u16, hf);
                } else {
                    w4[j] = (u16)f2bf1(r[j]);
                }
            }
            *(us4*)(PQ + (size_t)node*COUT + ch) = w4;
        }
    }
}

// pass1p: pull BN1a stats from f16 PQ1; 4 edges/iter.
__global__ __launch_bounds__(256) void k_pass1p(
    const u16* __restrict__ PQ1, const int* __restrict__ eps,
    const int* __restrict__ cursor, const int* __restrict__ deg,
    float* __restrict__ pblk, int N)
{
    int tid = threadIdx.x;
    int lane = tid & 63, wave = tid >> 6;
    float s0 = 0.f, s1 = 0.f, q0 = 0.f, q1 = 0.f;

    for (int n = blockIdx.x*4 + wave; n < N; n += gridDim.x*4){
        int d  = deg[n];
        int r0 = cursor[n] - d;
        f16x2 pv = *(const f16x2*)(PQ1 + (size_t)n*256 + 2*lane);
        int i = 0;
        for (; i + 3 < d; i += 4){
            int sA = eps[r0+i], sB = eps[r0+i+1], sC = eps[r0+i+2], sD = eps[r0+i+3];
            f16x2 qA = *(const f16x2*)(PQ1 + (size_t)sA*256 + 128 + 2*lane);
            f16x2 qB = *(const f16x2*)(PQ1 + (size_t)sB*256 + 128 + 2*lane);
            f16x2 qC = *(const f16x2*)(PQ1 + (size_t)sC*256 + 128 + 2*lane);
            f16x2 qD = *(const f16x2*)(PQ1 + (size_t)sD*256 + 128 + 2*lane);
            f16x2 hA = pv + qA, hB = pv + qB, hC = pv + qC, hD = pv + qD;
            float a0 = fmaxf((float)hA[0], 0.f), a1 = fmaxf((float)hA[1], 0.f);
            float b0 = fmaxf((float)hB[0], 0.f), b1 = fmaxf((float)hB[1], 0.f);
            float c0 = fmaxf((float)hC[0], 0.f), c1 = fmaxf((float)hC[1], 0.f);
            float e0 = fmaxf((float)hD[0], 0.f), e1 = fmaxf((float)hD[1], 0.f);
            s0 += (a0 + b0) + (c0 + e0); s1 += (a1 + b1) + (c1 + e1);
            q0 = fmaf(a0, a0, q0); q0 = fmaf(b0, b0, q0);
            q0 = fmaf(c0, c0, q0); q0 = fmaf(e0, e0, q0);
            q1 = fmaf(a1, a1, q1); q1 = fmaf(b1, b1, q1);
            q1 = fmaf(c1, c1, q1); q1 = fmaf(e1, e1, q1);
        }
        for (; i < d; ++i){
            int sA = eps[r0 + i];
            f16x2 qA = *(const f16x2*)(PQ1 + (size_t)sA*256 + 128 + 2*lane);
            f16x2 hA = pv + qA;
            float a0 = fmaxf((float)hA[0], 0.f), a1 = fmaxf((float)hA[1], 0.f);
            s0 += a0; s1 += a1;
            q0 = fmaf(a0, a0, q0);
            q1 = fmaf(a1, a1, q1);
        }
    }
    __shared__ float bS0[256], bS1[256], bQ0[256], bQ1[256];
    bS0[tid] = s0; bS1[tid] = s1; bQ0[tid] = q0; bQ1[tid] = q1;
    __syncthreads();
    if (wave == 0){
        float a0 = bS0[lane] + bS0[64+lane] + bS0[128+lane] + bS0[192+lane];
        float a1 = bS1[lane] + bS1[64+lane] + bS1[128+lane] + bS1[192+lane];
        float c0 = bQ0[lane] + bQ0[64+lane] + bQ0[128+lane] + bQ0[192+lane];
        float c1 = bQ1[lane] + bQ1[64+lane] + bQ1[128+lane] + bQ1[192+lane];
        atomicAdd(&pblk[2*lane],       a0);
        atomicAdd(&pblk[2*lane + 1],   a1);
        atomicAdd(&pblk[128 + 2*lane],     c0);
        atomicAdd(&pblk[128 + 2*lane + 1], c1);
    }
}

__global__ void k_fold1(const float* __restrict__ g1a, const float* __restrict__ bt1a,
                        const float* __restrict__ W1b, const float* __restrict__ b1b,
                        float* __restrict__ pblk, float fE)
{
    __shared__ float tS[128];
    int tid = threadIdx.x;
    if (tid < 128){
        float m = pblk[tid] * fE;
        float q = pblk[128 + tid] * fE;
        float v = fmaxf(q - m*m, 0.f);
        float s = g1a[tid] * rsqrtf(v + EPSBN);
        float t = bt1a[tid] - m*s;
        pblk[512 + tid] = s;
        pblk[640 + tid] = t;
        tS[tid] = t;
    }
    __syncthreads();
    if (tid < 64){
        float acc = b1b[tid];
        for (int k = 0; k < 128; k++) acc = fmaf(tS[k], W1b[k*64 + tid], acc);
        pblk[768 + tid] = acc;
    }
}

// pass2m: MFMA pull GEMM-b. Per node, 16 CSR-contiguous edges per group.
// B-frag: lane holds h[k = kt*32 + (lane>>4)*8 + j][edge = lane&15] (bf16)
// (the R6-proven spill layout). A = W' (s1a-folded W1b) in LDS, frag reads
// Wt2[swz(mt*16+lr, kt*32+lg*8)] (R9-proven). D: edge=lane&15,
// ch = mt*16 + (lane>>4)*4 + reg (proven). Stats + per-node max in regs.
__global__ __launch_bounds__(256) void k_pass2m(
    const u16* __restrict__ PQ1, const int* __restrict__ eps,
    const int* __restrict__ cursor, const int* __restrict__ deg,
    const float* __restrict__ W1b,
    float* __restrict__ pblk, float* __restrict__ agg, int N)
{
    __shared__ u16 Wt2[64*128];   // W'[ch][k] swizzled, shared by 4 waves
    int tid = threadIdx.x;
    for (int i = tid; i < 64*128; i += 256){
        int k = i >> 6, c = i & 63;
        Wt2[swz(c, k)] = (u16)f2bf1(W1b[i] * pblk[512 + k]);
    }
    __syncthreads();
    int lane = tid & 63, wave = tid >> 6;
    int lg = lane >> 4, le = lane & 15;
    float runS[16], runQ[16], bcr[16];
    #pragma unroll
    for (int i = 0; i < 16; i++){
        runS[i] = 0.f; runQ[i] = 0.f;
        bcr[i] = pblk[768 + (i >> 2)*16 + lg*4 + (i & 3)];
    }

    for (int n = blockIdx.x*4 + wave; n < N; n += gridDim.x*4){
        int d  = deg[n];
        if (d == 0) continue;
        int r0 = cursor[n] - d;
        // P octets for this lane's k-range (broadcast within 16-lane group)
        uint4 Praw[4];
        #pragma unroll
        for (int kt = 0; kt < 4; kt++)
            Praw[kt] = *(const uint4*)(PQ1 + (size_t)n*256 + kt*32 + lg*8);
        float nm[16];
        #pragma unroll
        for (int i = 0; i < 16; i++) nm[i] = -INFINITY;

        for (int base = 0; base < d; base += 16){
            int rem = d - base;
            int ei = base + (le < rem ? le : rem - 1);
            int s  = eps[r0 + ei];
            bool ev = le < rem;
            f32x4 acc0 = {0.f,0.f,0.f,0.f};
            f32x4 acc1 = {0.f,0.f,0.f,0.f};
            f32x4 acc2 = {0.f,0.f,0.f,0.f};
            f32x4 acc3 = {0.f,0.f,0.f,0.f};
            #pragma unroll
            for (int kt = 0; kt < 4; kt++){
                uint4 qv = *(const uint4*)(PQ1 + (size_t)s*256 + 128 + kt*32 + lg*8);
                uint4 bw;
                bw.x = hpack(Praw[kt].x, qv.x);
                bw.y = hpack(Praw[kt].y, qv.y);
                bw.z = hpack(Praw[kt].z, qv.z);
                bw.w = hpack(Praw[kt].w, qv.w);
                bf16x8 B = __builtin_bit_cast(bf16x8, bw);
                bf16x8 a0 = *(const bf16x8*)&Wt2[swz( 0 + le, kt*32 + lg*8)];
                bf16x8 a1 = *(const bf16x8*)&Wt2[swz(16 + le, kt*32 + lg*8)];
                bf16x8 a2 = *(const bf16x8*)&Wt2[swz(32 + le, kt*32 + lg*8)];
                bf16x8 a3 = *(const bf16x8*)&Wt2[swz(48 + le, kt*32 + lg*8)];
                acc0 = mfma16(a0, B, acc0);
                acc1 = mfma16(a1, B, acc1);
                acc2 = mfma16(a2, B, acc2);
                acc3 = mfma16(a3, B, acc3);
            }
            #pragma unroll
            for (int j = 0; j < 4; j++){
                float h0 = fmaxf(acc0[j] + bcr[j],      0.f);
                float h1 = fmaxf(acc1[j] + bcr[4 + j],  0.f);
                float h2 = fmaxf(acc2[j] + bcr[8 + j],  0.f);
                float h3 = fmaxf(acc3[j] + bcr[12 + j], 0.f);
                if (ev){
                    runS[j]      += h0; runQ[j]      = fmaf(h0, h0, runQ[j]);
                    runS[4 + j]  += h1; runQ[4 + j]  = fmaf(h1, h1, runQ[4 + j]);
                    runS[8 + j]  += h2; runQ[8 + j]  = fmaf(h2, h2, runQ[8 + j]);
                    runS[12 + j] += h3; runQ[12 + j] = fmaf(h3, h3, runQ[12 + j]);
                    nm[j]      = fmaxf(nm[j],      h0);
                    nm[4 + j]  = fmaxf(nm[4 + j],  h1);
                    nm[8 + j]  = fmaxf(nm[8 + j],  h2);
                    nm[12 + j] = fmaxf(nm[12 + j], h3);
                }
            }
        }
        // reduce node max across the 16 edge-lanes, then store (lane le==0)
        #pragma unroll
        for (int i = 0; i < 16; i++){
            float m = nm[i];
            m = fmaxf(m, __shfl_xor(m, 1, 16));
            m = fmaxf(m, __shfl_xor(m, 2, 16));
            m = fmaxf(m, __shfl_xor(m, 4, 16));
            m = fmaxf(m, __shfl_xor(m, 8, 16));
            nm[i] = m;
        }
        if (le == 0){
            #pragma unroll
            for (int i = 0; i < 16; i++)
                agg[(size_t)n*64 + (i >> 2)*16 + lg*4 + (i & 3)] = nm[i];
        }
    }
    #pragma unroll
    for (int i = 0; i < 16; i++){
        float s = runS[i], q = runQ[i];
        #pragma unroll
        for (int m = 1; m < 16; m <<= 1){ s += __shfl_xor(s, m); q += __shfl_xor(q, m); }
        if (le == 0){
            int ch = (i >> 2)*16 + lg*4 + (i & 3);
            atomicAdd(&pblk[256 + ch], s);
            atomicAdd(&pblk[320 + ch], q);
        }
    }
}

__global__ void k_fold_st(const float* __restrict__ g, const float* __restrict__ bt,
                          float* __restrict__ pblk, float fE, int so, int qo, int os, int ot)
{
    int tid = threadIdx.x;
    if (tid < 64){
        float m = pblk[so + tid] * fE;
        float q = pblk[qo + tid] * fE;
        float v = fmaxf(q - m*m, 0.f);
        float s = g[tid] * rsqrtf(v + EPSBN);
        pblk[os + tid] = s;
        pblk[ot + tid] = bt[tid] - m*s;
    }
}

// x1 = relu(bn1b(agg) or 0) -> x1b; reset agg to -inf for pass3p reuse.
__global__ void k_x1(float* __restrict__ agg, const float* __restrict__ pblk,
                     u16* __restrict__ x1b, int NF)
{
    int i = blockIdx.x*256 + threadIdx.x;
    if (i >= NF) return;
    int c = i & 63;
    float a = agg[i];
    float v = (a > -INFINITY) ? fmaf(a, pblk[832 + c], pblk[896 + c]) : 0.f;
    v = fmaxf(v, 0.f);
    x1b[i] = (u16)f2bf1(v);
    agg[i] = -INFINITY;
}

// pass3p: pull conv2 (stats2 + segmax Q2), 4 edges/iter.
__global__ __launch_bounds__(256) void k_pass3p(
    const u16* __restrict__ PQ2, const int* __restrict__ eps,
    const int* __restrict__ cursor, const int* __restrict__ deg,
    float* __restrict__ pblk, float* __restrict__ agg, int N)
{
    int tid = threadIdx.x;
    int lane = tid & 63, wave = tid >> 6;
    float runS = 0.f, runQ = 0.f;

    for (int n = blockIdx.x*4 + wave; n < N; n += gridDim.x*4){
        int d  = deg[n];
        int r0 = cursor[n] - d;
        float p = bf2f(PQ2[(size_t)n*128 + lane]);
        float mq = -INFINITY;
        int i = 0;
        for (; i + 3 < d; i += 4){
            int sA = eps[r0+i], sB = eps[r0+i+1], sC = eps[r0+i+2], sD = eps[r0+i+3];
            float qA = bf2f(PQ2[(size_t)sA*128 + 64 + lane]);
            float qB = bf2f(PQ2[(size_t)sB*128 + 64 + lane]);
            float qC = bf2f(PQ2[(size_t)sC*128 + 64 + lane]);
            float qD = bf2f(PQ2[(size_t)sD*128 + 64 + lane]);
            mq = fmaxf(mq, fmaxf(fmaxf(qA, qB), fmaxf(qC, qD)));
            float hA = fmaxf(p + qA, 0.f), hB = fmaxf(p + qB, 0.f);
            float hC = fmaxf(p + qC, 0.f), hD = fmaxf(p + qD, 0.f);
            runS += (hA + hB) + (hC + hD);
            runQ = fmaf(hA, hA, runQ); runQ = fmaf(hB, hB, runQ);
            runQ = fmaf(hC, hC, runQ); runQ = fmaf(hD, hD, runQ);
        }
        for (; i < d; ++i){
            int sA = eps[r0 + i];
            float qA = bf2f(PQ2[(size_t)sA*128 + 64 + lane]);
            mq = fmaxf(mq, qA);
            float hA = fmaxf(p + qA, 0.f);
            runS += hA;
            runQ = fmaf(hA, hA, runQ);
        }
        if (d > 0) agg[(size_t)n*64 + lane] = mq;
    }
    __shared__ float bS[256], bQ[256];
    bS[tid] = runS; bQ[tid] = runQ;
    __syncthreads();
    if (wave == 0){
        float s = bS[lane] + bS[64 + lane] + bS[128 + lane] + bS[192 + lane];
        float q = bQ[lane] + bQ[64 + lane] + bQ[128 + lane] + bQ[192 + lane];
        atomicAdd(&pblk[384 + lane], s);
        atomicAdd(&pblk[448 + lane], q);
    }
}

#define FUSE_NODES 32
__global__ __launch_bounds__(256) void k_fuse(const float* __restrict__ agg,
                                              const u16* __restrict__ x1b,
                                              const u16* __restrict__ PQ2,
                                              const int* __restrict__ batch,
                                              float* __restrict__ pblk, int N)
{
    int c = threadIdx.x & 63, r = threadIdx.x >> 6;
    int n0 = blockIdx.x*FUSE_NODES + r*(FUSE_NODES/4);
    if (n0 >= N) return;
    int n1 = n0 + FUSE_NODES/4; if (n1 > N) n1 = N;
    float s2c = pblk[960 + c], t2c = pblk[1024 + c];
    float gm = -INFINITY, gs = 0.f;
    int cur = batch[n0], cnt0 = 0;
    for (int n = n0; n < n1; ++n){
        int g = batch[n];
        if (g != cur){
            atomicMaxF(&pblk[1088 + cur*64 + c], gm);
            atomicAdd(&pblk[5184 + cur*64 + c], gs);
            if (c == 0) atomicAdd(&pblk[9280 + cur], (float)cnt0);
            gm = -INFINITY; gs = 0.f; cnt0 = 0; cur = g;
        }
        float a = agg[(size_t)n*64 + c];   // maxQ2 (or -inf if no in-edges)
        float v;
        if (a > -INFINITY){
            float p = bf2f(PQ2[(size_t)n*128 + c]);
            float pre = fmaxf(p + a, 0.f);
            v = fmaxf(fmaf(pre, s2c, t2c), 0.f);
        } else v = 0.f;
        float f = bf2f(x1b[(size_t)n*64 + c]) + v;
        gm = fmaxf(gm, f); gs += f; cnt0++;
    }
    atomicMaxF(&pblk[1088 + cur*64 + c], gm);
    atomicAdd(&pblk[5184 + cur*64 + c], gs);
    if (c == 0) atomicAdd(&pblk[9280 + cur], (float)cnt0);
}

__global__ void k_out(const float* __restrict__ pblk, float* __restrict__ out)
{
    int i = blockIdx.x*256 + threadIdx.x;
    if (i >= 64*128) return;
    int g = i >> 7, c = i & 127;
    float r;
    if (c < 64){
        float m = pblk[1088 + g*64 + c];
        r = (m > -INFINITY) ? m : 0.f;
    } else {
        float s = pblk[5184 + g*64 + (c - 64)];
        float n = pblk[9280 + g];
        r = s / fmaxf(n, 1.f);
    }
    out[i] = r;
}

extern "C" void kernel_launch(void* const* d_in, const int* in_sizes, int n_in,
                              void* d_out, int out_size, void* d_ws, size_t ws_size,
                              hipStream_t stream)
{
    const float* x    = (const float*)d_in[0];
    const int*   ei   = (const int*)  d_in[1];
    const int*   batch= (const int*)  d_in[2];
    const float* W1a  = (const float*)d_in[3];
    const float* b1a  = (const float*)d_in[4];
    const float* g1a  = (const float*)d_in[5];
    const float* bt1a = (const float*)d_in[6];
    const float* W1b  = (const float*)d_in[7];
    const float* b1b  = (const float*)d_in[8];
    const float* g1b  = (const float*)d_in[9];
    const float* bt1b = (const float*)d_in[10];
    const float* W2   = (const float*)d_in[11];
    const float* b2   = (const float*)d_in[12];
    const float* g2   = (const float*)d_in[13];
    const float* bt2  = (const float*)d_in[14];

    int N  = in_sizes[0] / 64;
    int E  = in_sizes[1] / 2;
    int NF = N * 64;

    char* ws = (char*)d_ws;
    size_t off = 0;
    auto alloc = [&](size_t bytes){ size_t o = off; off += (bytes + 255) & ~(size_t)255; return o; };
    u16*   xb    = (u16*)  (ws + alloc((size_t)NF*2));
    u16*   x1b   = (u16*)  (ws + alloc((size_t)NF*2));
    float* agg   = (float*)(ws + alloc((size_t)NF*4));
    float* pblk  = (float*)(ws + alloc((size_t)PB_TOT*4));
    int*   deg   = (int*)  (ws + alloc((size_t)N*4));
    int*   cursor= (int*)  (ws + alloc((size_t)N*4));
    int*   eps   = (int*)  (ws + alloc((size_t)E*4));
    u16*   PQ1   = (u16*)  (ws + alloc((size_t)N*256*2));
    u16*   PQ2   = (u16*)  (ws + alloc((size_t)N*128*2));
    int*   bsum  = (int*)  (ws + alloc((size_t)1024*4));
    int*   boff  = (int*)  (ws + alloc((size_t)1024*4));
    (void)ws_size;   // ~68MB << proven 237.7MB budget

    const int* esrc = ei;
    const int* edst = ei + E;
    int gElem  = (NF + 255) / 256;
    int gEdge  = (E + 255) / 256;
    int gNode  = (N + 63) / 64;
    int gScan  = (N + 1023) / 1024;
    int gPull  = ((N + 3) / 4) < 2048 ? ((N + 3) / 4) : 2048;
    float fE   = 1.f / (float)E;

    k_init        <<<gElem, 256, 0, stream>>>(x, xb, agg, pblk, deg, NF, N);
    k_hist        <<<gEdge, 256, 0, stream>>>(edst, deg, E);
    k_scanA       <<<gScan, 1024, 0, stream>>>(deg, cursor, bsum, N);
    k_scanB       <<<1, 64, 0, stream>>>(bsum, boff, gScan);
    k_scanC       <<<gScan, 1024, 0, stream>>>(cursor, boff, N);
    k_scatter     <<<gEdge, 256, 0, stream>>>(esrc, edst, cursor, eps, E);
    k_ngemm<256,1><<<gNode, 256, 0, stream>>>(xb, W1a, b1a, PQ1, N);
    k_pass1p      <<<gPull, 256, 0, stream>>>(PQ1, eps, cursor, deg, pblk, N);
    k_fold1       <<<1, 128, 0, stream>>>(g1a, bt1a, W1b, b1b, pblk, fE);
    k_pass2m      <<<gPull, 256, 0, stream>>>(PQ1, eps, cursor, deg, W1b, pblk, agg, N);
    k_fold_st     <<<1, 64, 0, stream>>>(g1b, bt1b, pblk, fE, 256, 320, 832, 896);
    k_x1          <<<gElem, 256, 0, stream>>>(agg, pblk, x1b, NF);
    k_ngemm<128,0><<<gNode, 256, 0, stream>>>(x1b, W2, b2, PQ2, N);
    k_pass3p      <<<gPull, 256, 0, stream>>>(PQ2, eps, cursor, deg, pblk, agg, N);
    k_fold_st     <<<1, 64, 0, stream>>>(g2, bt2, pblk, fE, 384, 448, 960, 1024);
    k_fuse        <<<(N + FUSE_NODES - 1)/FUSE_NODES, 256, 0, stream>>>(agg, x1b, PQ2, batch, pblk, N);
    k_out         <<<32, 256, 0, stream>>>(pblk, (float*)d_out);
}

// Round 18
// 713.100 us; speedup vs baseline: 1.8102x; 1.8102x over previous
//
#include <hip/hip_runtime.h>
#include <math.h>

// GraphNet: 2x EdgeConv (E=800k, F=H=64) + BN folded/commuted + pooling.
// R18: revert R17's MFMA-pull regression (848us @8% occ, 1-group-per-node
// starved the matrix pipe) back to the R16-proven VALU pull pass2p (282us
// @70% VALU, ~instruction floor for lane=channel fdot2). Keep R17's 4-edge
// ILP in pass1p/pass3p. Fold_st kernels inlined into k_x1/k_fuse (-2 launches).

typedef unsigned short u16;
typedef unsigned int   u32;
typedef __bf16 bf16x8 __attribute__((ext_vector_type(8)));
typedef float  f32x4  __attribute__((ext_vector_type(4)));
typedef unsigned short us4 __attribute__((ext_vector_type(4)));
typedef _Float16 f16;
typedef f16 f16x2 __attribute__((ext_vector_type(2)));

#define EPSBN 1e-5f
#define PB_TOT 9344
// pblk: 0:stS1a[128] 128:stQ1a[128] 256:stS1b 320:stQ1b 384:stS2 448:stQ2
// 512:s1a[128] 640:t1a[128] 768:b1bF[64] (832..1088 unused now)
// 1088:gmax[4096] 5184:gsum[4096] 9280:cnt[64]

#if __has_builtin(__builtin_amdgcn_fdot2)
#define HAS_FDOT2 1
#else
#define HAS_FDOT2 0
#endif
#if __has_builtin(__builtin_amdgcn_readlane)
#define RLANE(v, l) ((u32)__builtin_amdgcn_readlane((int)(v), (l)))
#else
#define RLANE(v, l) ((u32)__shfl((int)(v), (l), 64))
#endif

__device__ __forceinline__ u32 f2bf1(float f){
    u32 u = __float_as_uint(f);
    return (u + 0x7FFFu + ((u >> 16) & 1u)) >> 16;
}
__device__ __forceinline__ float bf2f(u16 b){
    return __uint_as_float(((u32)b) << 16);
}
__device__ __forceinline__ void atomicMaxF(float* a, float v){
    if (v >= 0.f) atomicMax((int*)a, __float_as_int(v));
    else          atomicMin((u32*)a, __float_as_uint(v));
}
__device__ __forceinline__ int swz64(int row, int k){
    return row*64 + (k ^ ((row & 7) << 3));
}
__device__ __forceinline__ f32x4 mfma16(bf16x8 a, bf16x8 b, f32x4 c){
    return __builtin_amdgcn_mfma_f32_16x16x32_bf16(a, b, c, 0, 0, 0);
}
__device__ __forceinline__ float fdot2f(u32 h, f16x2 w, float acc){
#if HAS_FDOT2
    return __builtin_amdgcn_fdot2(__builtin_bit_cast(f16x2, h), w, acc, false);
#else
    f16x2 hh = __builtin_bit_cast(f16x2, h);
    acc = fmaf((float)hh[0], (float)w[0], acc);
    return fmaf((float)hh[1], (float)w[1], acc);
#endif
}

__global__ void k_init(const float* __restrict__ x, u16* __restrict__ xb,
                       float* __restrict__ agg,
                       float* __restrict__ pblk, int* __restrict__ deg,
                       int NF, int N){
    int i = blockIdx.x*256 + threadIdx.x;
    if (i < NF){
        xb[i] = (u16)f2bf1(x[i]);
        agg[i] = -INFINITY;
    }
    if (i < N) deg[i] = 0;
    if (i < PB_TOT){
        pblk[i] = (i >= 1088 && i < 5184) ? -INFINITY : 0.f;
    }
}

__global__ void k_hist(const int* __restrict__ edst, int* __restrict__ deg, int E){
    int e = blockIdx.x*256 + threadIdx.x;
    if (e < E) atomicAdd(&deg[edst[e]], 1);
}

// 3-kernel parallel exclusive scan of deg -> cursor.
__global__ __launch_bounds__(1024) void k_scanA(const int* __restrict__ deg,
                                                int* __restrict__ cursor,
                                                int* __restrict__ bsum, int N){
    __shared__ int buf[1024];
    int tid = threadIdx.x;
    int i = blockIdx.x*1024 + tid;
    int v = (i < N) ? deg[i] : 0;
    buf[tid] = v;
    __syncthreads();
    #pragma unroll
    for (int s = 1; s < 1024; s <<= 1){
        int a = (tid >= s) ? buf[tid - s] : 0;
        __syncthreads();
        buf[tid] += a;
        __syncthreads();
    }
    if (i < N) cursor[i] = buf[tid] - v;
    if (tid == 1023) bsum[blockIdx.x] = buf[1023];
}
__global__ void k_scanB(const int* __restrict__ bsum, int* __restrict__ boff, int nblk){
    if (threadIdx.x == 0){
        int run = 0;
        for (int i = 0; i < nblk; ++i){ boff[i] = run; run += bsum[i]; }
    }
}
__global__ __launch_bounds__(1024) void k_scanC(int* __restrict__ cursor,
                                                const int* __restrict__ boff, int N){
    int i = blockIdx.x*1024 + threadIdx.x;
    if (i < N) cursor[i] += boff[blockIdx.x];
}

__global__ void k_scatter(const int* __restrict__ esrc, const int* __restrict__ edst,
                          int* __restrict__ cursor, int* __restrict__ eps, int E){
    int e = blockIdx.x*256 + threadIdx.x;
    if (e < E){
        int d = edst[e];
        int pos = atomicAdd(&cursor[d], 1);
        eps[pos] = esrc[e];
    }
}

// Node GEMM -> PQ table. FMT=0: bf16 out; FMT=1: f16 out.
template<int COUT, int FMT>
__global__ __launch_bounds__(256) void k_ngemm(
    const u16* __restrict__ xin, const float* __restrict__ Wsrc,
    const float* __restrict__ bias, u16* __restrict__ PQ, int N)
{
    const int WC = COUT/2;
    __shared__ u16 Wt[COUT*64];
    __shared__ u16 At[64*64];
    int tid = threadIdx.x;
    for (int i = tid; i < COUT*64; i += 256){
        int c = i >> 6, k = i & 63;
        float w = (c < WC) ? (Wsrc[k*WC + c] - Wsrc[(64+k)*WC + c])
                           : Wsrc[(64+k)*WC + (c - WC)];
        Wt[swz64(c, k)] = (u16)f2bf1(w);
    }
    int t = blockIdx.x;
    for (int i = tid; i < 512; i += 256){
        int row = i >> 3, ck = i & 7;
        int node = t*64 + row;
        uint4 v;
        if (node < N) v = *(const uint4*)(xin + (size_t)node*64 + ck*8);
        else { v.x = v.y = v.z = v.w = 0u; }
        *(uint4*)&At[swz64(row, ck*8)] = v;
    }
    __syncthreads();
    int lane = tid & 63, wave = tid >> 6;
    int lg = lane >> 4, lr = lane & 15;
    int row = wave*16 + lr;
    bf16x8 bfr[2];
    #pragma unroll
    for (int kt = 0; kt < 2; kt++)
        bfr[kt] = *(const bf16x8*)&At[swz64(row, kt*32 + lg*8)];
    int node = t*64 + wave*16 + lr;
    #pragma unroll
    for (int mt = 0; mt < COUT/16; mt++){
        f32x4 acc = {0.f,0.f,0.f,0.f};
        #pragma unroll
        for (int kt = 0; kt < 2; kt++){
            bf16x8 af = *(const bf16x8*)&Wt[swz64(mt*16 + lr, kt*32 + lg*8)];
            acc = mfma16(af, bfr[kt], acc);
        }
        int ch = mt*16 + lg*4;
        float r[4] = {acc[0], acc[1], acc[2], acc[3]};
        if (ch < WC){
            float4 bb = *(const float4*)(bias + ch);
            r[0] += bb.x; r[1] += bb.y; r[2] += bb.z; r[3] += bb.w;
        }
        if (node < N){
            us4 w4;
            #pragma unroll
            for (int j = 0; j < 4; j++){
                if (FMT){
                    f16 hf = (f16)r[j];
                    w4[j] = __builtin_bit_cast(u16, hf);
                } else {
                    w4[j] = (u16)f2bf1(r[j]);
                }
            }
            *(us4*)(PQ + (size_t)node*COUT + ch) = w4;
        }
    }
}

// pass1p: pull BN1a stats from f16 PQ1; 4 edges/iter.
__global__ __launch_bounds__(256) void k_pass1p(
    const u16* __restrict__ PQ1, const int* __restrict__ eps,
    const int* __restrict__ cursor, const int* __restrict__ deg,
    float* __restrict__ pblk, int N)
{
    int tid = threadIdx.x;
    int lane = tid & 63, wave = tid >> 6;
    float s0 = 0.f, s1 = 0.f, q0 = 0.f, q1 = 0.f;

    for (int n = blockIdx.x*4 + wave; n < N; n += gridDim.x*4){
        int d  = deg[n];
        int r0 = cursor[n] - d;
        f16x2 pv = *(const f16x2*)(PQ1 + (size_t)n*256 + 2*lane);
        int i = 0;
        for (; i + 3 < d; i += 4){
            int sA = eps[r0+i], sB = eps[r0+i+1], sC = eps[r0+i+2], sD = eps[r0+i+3];
            f16x2 qA = *(const f16x2*)(PQ1 + (size_t)sA*256 + 128 + 2*lane);
            f16x2 qB = *(const f16x2*)(PQ1 + (size_t)sB*256 + 128 + 2*lane);
            f16x2 qC = *(const f16x2*)(PQ1 + (size_t)sC*256 + 128 + 2*lane);
            f16x2 qD = *(const f16x2*)(PQ1 + (size_t)sD*256 + 128 + 2*lane);
            f16x2 hA = pv + qA, hB = pv + qB, hC = pv + qC, hD = pv + qD;
            float a0 = fmaxf((float)hA[0], 0.f), a1 = fmaxf((float)hA[1], 0.f);
            float b0 = fmaxf((float)hB[0], 0.f), b1 = fmaxf((float)hB[1], 0.f);
            float c0 = fmaxf((float)hC[0], 0.f), c1 = fmaxf((float)hC[1], 0.f);
            float e0 = fmaxf((float)hD[0], 0.f), e1 = fmaxf((float)hD[1], 0.f);
            s0 += (a0 + b0) + (c0 + e0); s1 += (a1 + b1) + (c1 + e1);
            q0 = fmaf(a0, a0, q0); q0 = fmaf(b0, b0, q0);
            q0 = fmaf(c0, c0, q0); q0 = fmaf(e0, e0, q0);
            q1 = fmaf(a1, a1, q1); q1 = fmaf(b1, b1, q1);
            q1 = fmaf(c1, c1, q1); q1 = fmaf(e1, e1, q1);
        }
        for (; i < d; ++i){
            int sA = eps[r0 + i];
            f16x2 qA = *(const f16x2*)(PQ1 + (size_t)sA*256 + 128 + 2*lane);
            f16x2 hA = pv + qA;
            float a0 = fmaxf((float)hA[0], 0.f), a1 = fmaxf((float)hA[1], 0.f);
            s0 += a0; s1 += a1;
            q0 = fmaf(a0, a0, q0);
            q1 = fmaf(a1, a1, q1);
        }
    }
    __shared__ float bS0[256], bS1[256], bQ0[256], bQ1[256];
    bS0[tid] = s0; bS1[tid] = s1; bQ0[tid] = q0; bQ1[tid] = q1;
    __syncthreads();
    if (wave == 0){
        float a0 = bS0[lane] + bS0[64+lane] + bS0[128+lane] + bS0[192+lane];
        float a1 = bS1[lane] + bS1[64+lane] + bS1[128+lane] + bS1[192+lane];
        float c0 = bQ0[lane] + bQ0[64+lane] + bQ0[128+lane] + bQ0[192+lane];
        float c1 = bQ1[lane] + bQ1[64+lane] + bQ1[128+lane] + bQ1[192+lane];
        atomicAdd(&pblk[2*lane],       a0);
        atomicAdd(&pblk[2*lane + 1],   a1);
        atomicAdd(&pblk[128 + 2*lane],     c0);
        atomicAdd(&pblk[128 + 2*lane + 1], c1);
    }
}

__global__ void k_fold1(const float* __restrict__ g1a, const float* __restrict__ bt1a,
                        const float* __restrict__ W1b, const float* __restrict__ b1b,
                        float* __restrict__ pblk, float fE)
{
    __shared__ float tS[128];
    int tid = threadIdx.x;
    if (tid < 128){
        float m = pblk[tid] * fE;
        float q = pblk[128 + tid] * fE;
        float v = fmaxf(q - m*m, 0.f);
        float s = g1a[tid] * rsqrtf(v + EPSBN);
        float t = bt1a[tid] - m*s;
        pblk[512 + tid] = s;
        pblk[640 + tid] = t;
        tS[tid] = t;
    }
    __syncthreads();
    if (tid < 64){
        float acc = b1b[tid];
        for (int k = 0; k < 128; k++) acc = fmaf(tS[k], W1b[k*64 + tid], acc);
        pblk[768 + tid] = acc;
    }
}

// pass2p: pull GEMM-b, 2 edges/iter x 4 accumulators; readlane + fdot2.
// (R16-proven: 282us @ ~70% VALUBusy — the lane=channel instruction floor.)
__global__ __launch_bounds__(256) void k_pass2p(
    const u16* __restrict__ PQ1, const int* __restrict__ eps,
    const int* __restrict__ cursor, const int* __restrict__ deg,
    const float* __restrict__ W1b,
    float* __restrict__ pblk, float* __restrict__ agg, int N)
{
    int tid = threadIdx.x;
    int lane = tid & 63, wave = tid >> 6;
    f16x2 wh[64];
    #pragma unroll
    for (int kk = 0; kk < 64; kk++){
        float w0 = pblk[512 + 2*kk]     * W1b[(2*kk)*64 + lane];
        float w1 = pblk[512 + 2*kk + 1] * W1b[(2*kk + 1)*64 + lane];
        f16x2 t; t[0] = (f16)w0; t[1] = (f16)w1;
        wh[kk] = t;
    }
    float bc = pblk[768 + lane];
    float runS = 0.f, runQ = 0.f;
    const f16 z0 = (f16)0;

    for (int n = blockIdx.x*4 + wave; n < N; n += gridDim.x*4){
        int d  = deg[n];
        int r0 = cursor[n] - d;
        f16x2 pv = *(const f16x2*)(PQ1 + (size_t)n*256 + 2*lane);
        float mh = -INFINITY;
        int i = 0;
        for (; i + 1 < d; i += 2){
            int sA = eps[r0 + i];
            int sB = eps[r0 + i + 1];
            f16x2 qA = *(const f16x2*)(PQ1 + (size_t)sA*256 + 128 + 2*lane);
            f16x2 qB = *(const f16x2*)(PQ1 + (size_t)sB*256 + 128 + 2*lane);
            f16x2 hA = pv + qA, hB = pv + qB;
            hA[0] = hA[0] > z0 ? hA[0] : z0;  hA[1] = hA[1] > z0 ? hA[1] : z0;
            hB[0] = hB[0] > z0 ? hB[0] : z0;  hB[1] = hB[1] > z0 ? hB[1] : z0;
            u32 hpA = __builtin_bit_cast(u32, hA);
            u32 hpB = __builtin_bit_cast(u32, hB);
            float aA[4] = {0.f,0.f,0.f,0.f};
            float aB[4] = {0.f,0.f,0.f,0.f};
            #pragma unroll
            for (int kk = 0; kk < 64; kk++){
                u32 xA = RLANE(hpA, kk);
                u32 xB = RLANE(hpB, kk);
                aA[kk & 3] = fdot2f(xA, wh[kk], aA[kk & 3]);
                aB[kk & 3] = fdot2f(xB, wh[kk], aB[kk & 3]);
            }
            float hbA = fmaxf((aA[0]+aA[1]) + (aA[2]+aA[3]) + bc, 0.f);
            float hbB = fmaxf((aB[0]+aB[1]) + (aB[2]+aB[3]) + bc, 0.f);
            runS += hbA + hbB;
            runQ = fmaf(hbA, hbA, runQ);
            runQ = fmaf(hbB, hbB, runQ);
            mh = fmaxf(mh, fmaxf(hbA, hbB));
        }
        if (i < d){
            int sA = eps[r0 + i];
            f16x2 qA = *(const f16x2*)(PQ1 + (size_t)sA*256 + 128 + 2*lane);
            f16x2 hA = pv + qA;
            hA[0] = hA[0] > z0 ? hA[0] : z0;  hA[1] = hA[1] > z0 ? hA[1] : z0;
            u32 hpA = __builtin_bit_cast(u32, hA);
            float aA[4] = {0.f,0.f,0.f,0.f};
            #pragma unroll
            for (int kk = 0; kk < 64; kk++){
                u32 xA = RLANE(hpA, kk);
                aA[kk & 3] = fdot2f(xA, wh[kk], aA[kk & 3]);
            }
            float hbA = fmaxf((aA[0]+aA[1]) + (aA[2]+aA[3]) + bc, 0.f);
            runS += hbA;
            runQ = fmaf(hbA, hbA, runQ);
            mh = fmaxf(mh, hbA);
        }
        if (d > 0) agg[(size_t)n*64 + lane] = mh;
    }
    __shared__ float bS[256], bQ[256];
    bS[tid] = runS; bQ[tid] = runQ;
    __syncthreads();
    if (wave == 0){
        float s = bS[lane] + bS[64+lane] + bS[128+lane] + bS[192+lane];
        float q = bQ[lane] + bQ[64+lane] + bQ[128+lane] + bQ[192+lane];
        atomicAdd(&pblk[256 + lane], s);
        atomicAdd(&pblk[320 + lane], q);
    }
}

// x1 = relu(bn1b(agg) or 0) -> x1b; BN1b affine computed inline from raw
// stats (fold_st absorbed). Resets agg to -inf for pass3p reuse.
__global__ void k_x1(float* __restrict__ agg, const float* __restrict__ pblk,
                     const float* __restrict__ g1b, const float* __restrict__ bt1b,
                     float fE, u16* __restrict__ x1b, int NF)
{
    int i = blockIdx.x*256 + threadIdx.x;
    if (i >= NF) return;
    int c = i & 63;
    float m = pblk[256 + c] * fE;
    float q = pblk[320 + c] * fE;
    float vv = fmaxf(q - m*m, 0.f);
    float s = g1b[c] * rsqrtf(vv + EPSBN);
    float t = bt1b[c] - m*s;
    float a = agg[i];
    float v = (a > -INFINITY) ? fmaf(a, s, t) : 0.f;
    v = fmaxf(v, 0.f);
    x1b[i] = (u16)f2bf1(v);
    agg[i] = -INFINITY;
}

// pass3p: pull conv2 (stats2 + segmax Q2), 4 edges/iter.
__global__ __launch_bounds__(256) void k_pass3p(
    const u16* __restrict__ PQ2, const int* __restrict__ eps,
    const int* __restrict__ cursor, const int* __restrict__ deg,
    float* __restrict__ pblk, float* __restrict__ agg, int N)
{
    int tid = threadIdx.x;
    int lane = tid & 63, wave = tid >> 6;
    float runS = 0.f, runQ = 0.f;

    for (int n = blockIdx.x*4 + wave; n < N; n += gridDim.x*4){
        int d  = deg[n];
        int r0 = cursor[n] - d;
        float p = bf2f(PQ2[(size_t)n*128 + lane]);
        float mq = -INFINITY;
        int i = 0;
        for (; i + 3 < d; i += 4){
            int sA = eps[r0+i], sB = eps[r0+i+1], sC = eps[r0+i+2], sD = eps[r0+i+3];
            float qA = bf2f(PQ2[(size_t)sA*128 + 64 + lane]);
            float qB = bf2f(PQ2[(size_t)sB*128 + 64 + lane]);
            float qC = bf2f(PQ2[(size_t)sC*128 + 64 + lane]);
            float qD = bf2f(PQ2[(size_t)sD*128 + 64 + lane]);
            mq = fmaxf(mq, fmaxf(fmaxf(qA, qB), fmaxf(qC, qD)));
            float hA = fmaxf(p + qA, 0.f), hB = fmaxf(p + qB, 0.f);
            float hC = fmaxf(p + qC, 0.f), hD = fmaxf(p + qD, 0.f);
            runS += (hA + hB) + (hC + hD);
            runQ = fmaf(hA, hA, runQ); runQ = fmaf(hB, hB, runQ);
            runQ = fmaf(hC, hC, runQ); runQ = fmaf(hD, hD, runQ);
        }
        for (; i < d; ++i){
            int sA = eps[r0 + i];
            float qA = bf2f(PQ2[(size_t)sA*128 + 64 + lane]);
            mq = fmaxf(mq, qA);
            float hA = fmaxf(p + qA, 0.f);
            runS += hA;
            runQ = fmaf(hA, hA, runQ);
        }
        if (d > 0) agg[(size_t)n*64 + lane] = mq;
    }
    __shared__ float bS[256], bQ[256];
    bS[tid] = runS; bQ[tid] = runQ;
    __syncthreads();
    if (wave == 0){
        float s = bS[lane] + bS[64 + lane] + bS[128 + lane] + bS[192 + lane];
        float q = bQ[lane] + bQ[64 + lane] + bQ[128 + lane] + bQ[192 + lane];
        atomicAdd(&pblk[384 + lane], s);
        atomicAdd(&pblk[448 + lane], q);
    }
}

// k_fuse: BN2 affine computed inline from raw stats (fold_st absorbed);
// x2 reconstructed from maxQ2+P2; per-run graph pooling.
#define FUSE_NODES 32
__global__ __launch_bounds__(256) void k_fuse(const float* __restrict__ agg,
                                              const u16* __restrict__ x1b,
                                              const u16* __restrict__ PQ2,
                                              const int* __restrict__ batch,
                                              const float* __restrict__ g2,
                                              const float* __restrict__ bt2,
                                              float fE,
                                              float* __restrict__ pblk, int N)
{
    int c = threadIdx.x & 63, r = threadIdx.x >> 6;
    int n0 = blockIdx.x*FUSE_NODES + r*(FUSE_NODES/4);
    if (n0 >= N) return;
    int n1 = n0 + FUSE_NODES/4; if (n1 > N) n1 = N;
    float m2 = pblk[384 + c] * fE;
    float q2 = pblk[448 + c] * fE;
    float vv = fmaxf(q2 - m2*m2, 0.f);
    float s2c = g2[c] * rsqrtf(vv + EPSBN);
    float t2c = bt2[c] - m2*s2c;
    float gm = -INFINITY, gs = 0.f;
    int cur = batch[n0], cnt0 = 0;
    for (int n = n0; n < n1; ++n){
        int g = batch[n];
        if (g != cur){
            atomicMaxF(&pblk[1088 + cur*64 + c], gm);
            atomicAdd(&pblk[5184 + cur*64 + c], gs);
            if (c == 0) atomicAdd(&pblk[9280 + cur], (float)cnt0);
            gm = -INFINITY; gs = 0.f; cnt0 = 0; cur = g;
        }
        float a = agg[(size_t)n*64 + c];   // maxQ2 (or -inf if no in-edges)
        float v;
        if (a > -INFINITY){
            float p = bf2f(PQ2[(size_t)n*128 + c]);
            float pre = fmaxf(p + a, 0.f);
            v = fmaxf(fmaf(pre, s2c, t2c), 0.f);
        } else v = 0.f;
        float f = bf2f(x1b[(size_t)n*64 + c]) + v;
        gm = fmaxf(gm, f); gs += f; cnt0++;
    }
    atomicMaxF(&pblk[1088 + cur*64 + c], gm);
    atomicAdd(&pblk[5184 + cur*64 + c], gs);
    if (c == 0) atomicAdd(&pblk[9280 + cur], (float)cnt0);
}

__global__ void k_out(const float* __restrict__ pblk, float* __restrict__ out)
{
    int i = blockIdx.x*256 + threadIdx.x;
    if (i >= 64*128) return;
    int g = i >> 7, c = i & 127;
    float r;
    if (c < 64){
        float m = pblk[1088 + g*64 + c];
        r = (m > -INFINITY) ? m : 0.f;
    } else {
        float s = pblk[5184 + g*64 + (c - 64)];
        float n = pblk[9280 + g];
        r = s / fmaxf(n, 1.f);
    }
    out[i] = r;
}

extern "C" void kernel_launch(void* const* d_in, const int* in_sizes, int n_in,
                              void* d_out, int out_size, void* d_ws, size_t ws_size,
                              hipStream_t stream)
{
    const float* x    = (const float*)d_in[0];
    const int*   ei   = (const int*)  d_in[1];
    const int*   batch= (const int*)  d_in[2];
    const float* W1a  = (const float*)d_in[3];
    const float* b1a  = (const float*)d_in[4];
    const float* g1a  = (const float*)d_in[5];
    const float* bt1a = (const float*)d_in[6];
    const float* W1b  = (const float*)d_in[7];
    const float* b1b  = (const float*)d_in[8];
    const float* g1b  = (const float*)d_in[9];
    const float* bt1b = (const float*)d_in[10];
    const float* W2   = (const float*)d_in[11];
    const float* b2   = (const float*)d_in[12];
    const float* g2   = (const float*)d_in[13];
    const float* bt2  = (const float*)d_in[14];

    int N  = in_sizes[0] / 64;
    int E  = in_sizes[1] / 2;
    int NF = N * 64;

    char* ws = (char*)d_ws;
    size_t off = 0;
    auto alloc = [&](size_t bytes){ size_t o = off; off += (bytes + 255) & ~(size_t)255; return o; };
    u16*   xb    = (u16*)  (ws + alloc((size_t)NF*2));
    u16*   x1b   = (u16*)  (ws + alloc((size_t)NF*2));
    float* agg   = (float*)(ws + alloc((size_t)NF*4));
    float* pblk  = (float*)(ws + alloc((size_t)PB_TOT*4));
    int*   deg   = (int*)  (ws + alloc((size_t)N*4));
    int*   cursor= (int*)  (ws + alloc((size_t)N*4));
    int*   eps   = (int*)  (ws + alloc((size_t)E*4));
    u16*   PQ1   = (u16*)  (ws + alloc((size_t)N*256*2));
    u16*   PQ2   = (u16*)  (ws + alloc((size_t)N*128*2));
    int*   bsum  = (int*)  (ws + alloc((size_t)1024*4));
    int*   boff  = (int*)  (ws + alloc((size_t)1024*4));
    (void)ws_size;   // ~68MB << proven 237.7MB budget

    const int* esrc = ei;
    const int* edst = ei + E;
    int gElem  = (NF + 255) / 256;
    int gEdge  = (E + 255) / 256;
    int gNode  = (N + 63) / 64;
    int gScan  = (N + 1023) / 1024;
    int gPull  = ((N + 3) / 4) < 2048 ? ((N + 3) / 4) : 2048;
    float fE   = 1.f / (float)E;

    k_init        <<<gElem, 256, 0, stream>>>(x, xb, agg, pblk, deg, NF, N);
    k_hist        <<<gEdge, 256, 0, stream>>>(edst, deg, E);
    k_scanA       <<<gScan, 1024, 0, stream>>>(deg, cursor, bsum, N);
    k_scanB       <<<1, 64, 0, stream>>>(bsum, boff, gScan);
    k_scanC       <<<gScan, 1024, 0, stream>>>(cursor, boff, N);
    k_scatter     <<<gEdge, 256, 0, stream>>>(esrc, edst, cursor, eps, E);
    k_ngemm<256,1><<<gNode, 256, 0, stream>>>(xb, W1a, b1a, PQ1, N);
    k_pass1p      <<<gPull, 256, 0, stream>>>(PQ1, eps, cursor, deg, pblk, N);
    k_fold1       <<<1, 128, 0, stream>>>(g1a, bt1a, W1b, b1b, pblk, fE);
    k_pass2p      <<<gPull, 256, 0, stream>>>(PQ1, eps, cursor, deg, W1b, pblk, agg, N);
    k_x1          <<<gElem, 256, 0, stream>>>(agg, pblk, g1b, bt1b, fE, x1b, NF);
    k_ngemm<128,0><<<gNode, 256, 0, stream>>>(x1b, W2, b2, PQ2, N);
    k_pass3p      <<<gPull, 256, 0, stream>>>(PQ2, eps, cursor, deg, pblk, agg, N);
    k_fuse        <<<(N + FUSE_NODES - 1)/FUSE_NODES, 256, 0, stream>>>(agg, x1b, PQ2, batch, g2, bt2, fE, pblk, N);
    k_out         <<<32, 256, 0, stream>>>(pblk, (float*)d_out);
}